// Round 3
// baseline (12340.168 us; speedup 1.0000x reference)
//
#include <hip/hip_runtime.h>
#include <hip/hip_cooperative_groups.h>
#include <math.h>

#define H    1024
#define H3   3072
#define DIN  512
#define VSZ  32000
#define SS   64
#define BB   128
#define TP   47
#define NROWS (TP*BB)      // 6016
#define VCHUNKS 250        // 32000 / 128
#define FMARGIN 0.1f

typedef unsigned short u16;
typedef __bf16 bf16_t;
typedef bf16_t bf16x8 __attribute__((ext_vector_type(8)));
typedef float f32x4 __attribute__((ext_vector_type(4)));
typedef u16 u16x4 __attribute__((ext_vector_type(4)));
typedef u16 u16x8 __attribute__((ext_vector_type(8)));

__device__ inline u16 f2bf(float f){
    unsigned b = __float_as_uint(f);
    return (u16)((b + 0x7FFFu + ((b >> 16) & 1u)) >> 16);
}
__device__ inline float bf2f(u16 u){ return __uint_as_float(((unsigned)u) << 16); }
__device__ inline float sigm(float x){ return 1.f/(1.f + expf(-x)); }

__device__ inline void stoval(float* p, float v){ *p = v; }
__device__ inline void stoval(u16* p, float v){ *p = f2bf(v); }

// ---------- small helpers ----------

__global__ __launch_bounds__(128) void k_mask_sum(const float* __restrict__ mask, float* __restrict__ msum){
    int b = threadIdx.x;
    if (b < BB){ float s = 0.f; for (int i = 0; i < SS; i++) s += mask[i*BB + b]; msum[b] = s; }
}

__global__ __launch_bounds__(256) void k_mean_ctx(const float* __restrict__ ctx, const float* __restrict__ msum,
                                                  float* __restrict__ mean){
    int idx = blockIdx.x*256 + threadIdx.x;
    if (idx < BB*H){
        float s = 0.f;
        for (int i = 0; i < SS; i++) s += ctx[(size_t)i*BB*H + idx];
        mean[idx] = s / msum[idx / H];
    }
}

// row-major f32 -> row-major bf16
__global__ __launch_bounds__(256) void k_f32bf(const float* __restrict__ in, u16* __restrict__ out, int n4){
    int i = blockIdx.x*256 + threadIdx.x;
    if (i >= n4) return;
    float4 v = ((const float4*)in)[i];
    u16x4 o = { f2bf(v.x), f2bf(v.y), f2bf(v.z), f2bf(v.w) };
    ((u16x4*)out)[i] = o;
}

// row-major f32 (R x K) -> MFMA-fragment-ordered bf16: [rt][k0][lane][8]
// offset(r,k) = ((r>>4)*(K/32) + (k>>5))*512 + ((r&15) + ((k>>3)&3)*16)*8 + (k&7)
__global__ __launch_bounds__(256) void k_f2bf_frag(const float* __restrict__ in, u16* __restrict__ out,
                                                   int RK8, int K8){
    int t = blockIdx.x*256 + threadIdx.x;
    if (t >= RK8) return;
    int r = t / K8, k8 = t - r*K8;
    const float* p = in + (size_t)r*K8*8 + k8*8;
    float4 a = *(const float4*)p;
    float4 b = *(const float4*)(p + 4);
    size_t dst = ((size_t)(r >> 4)*(K8 >> 2) + (k8 >> 2))*512 + (size_t)((r & 15) + (k8 & 3)*16)*8;
    u16x8 o;
    o[0]=f2bf(a.x); o[1]=f2bf(a.y); o[2]=f2bf(a.z); o[3]=f2bf(a.w);
    o[4]=f2bf(b.x); o[5]=f2bf(b.y); o[6]=f2bf(b.z); o[7]=f2bf(b.w);
    *(u16x8*)(out + dst) = o;
}

// rows of 512 f32: L2-normalize -> frag-ordered bf16 (K=512, K32=16)
__global__ __launch_bounds__(256) void k_rownorm_frag(const float* __restrict__ in, u16* __restrict__ out,
                                                      int nrows){
    int w = threadIdx.x >> 6, lane = threadIdx.x & 63;
    int row = blockIdx.x*4 + w;
    if (row >= nrows) return;
    const float* r = in + (size_t)row*512 + lane*8;
    float4 a = *(const float4*)r;
    float4 b = *(const float4*)(r + 4);
    float s = a.x*a.x + a.y*a.y + a.z*a.z + a.w*a.w
            + b.x*b.x + b.y*b.y + b.z*b.z + b.w*b.w;
    #pragma unroll
    for (int off = 32; off; off >>= 1) s += __shfl_xor(s, off);
    float inv = rsqrtf(s);
    size_t dst = ((size_t)(row >> 4)*16 + (lane >> 2))*512 + (size_t)((row & 15) + (lane & 3)*16)*8;
    u16x8 o;
    o[0]=f2bf(a.x*inv); o[1]=f2bf(a.y*inv); o[2]=f2bf(a.z*inv); o[3]=f2bf(a.w*inv);
    o[4]=f2bf(b.x*inv); o[5]=f2bf(b.y*inv); o[6]=f2bf(b.z*inv); o[7]=f2bf(b.w*inv);
    *(u16x8*)(out + dst) = o;
}

// gather emb_W[y[row]] -> frag-ordered bf16 rows (K=512)
__global__ __launch_bounds__(256) void k_emb_frag(const float* __restrict__ emb, const int* __restrict__ y,
                                                  u16* __restrict__ out){
    int w = threadIdx.x >> 6, lane = threadIdx.x & 63;
    int row = blockIdx.x*4 + w;            // < 6016
    int src = y[row];
    const float* r = emb + (size_t)src*512 + lane*8;
    float4 a = *(const float4*)r;
    float4 b = *(const float4*)(r + 4);
    size_t dst = ((size_t)(row >> 4)*16 + (lane >> 2))*512 + (size_t)((row & 15) + (lane & 3)*16)*8;
    u16x8 o;
    o[0]=f2bf(a.x); o[1]=f2bf(a.y); o[2]=f2bf(a.z); o[3]=f2bf(a.w);
    o[4]=f2bf(b.x); o[5]=f2bf(b.y); o[6]=f2bf(b.z); o[7]=f2bf(b.w);
    *(u16x8*)(out + dst) = o;
}

// ---------- fp32 GEMM (h0 init only) ----------
template<int ACT>
__global__ __launch_bounds__(256) void k_gemm_nt(const float* __restrict__ A, const float* __restrict__ W,
                                                 const float* __restrict__ bias, float* __restrict__ C,
                                                 int M, int N, int K){
    __shared__ float As[16][68];
    __shared__ float Ws[16][68];
    int tid = threadIdx.x;
    int bm = blockIdx.y*64, bn = blockIdx.x*64;
    int lr = tid >> 2;
    int lk = (tid & 3) * 4;
    int tr = (tid >> 4) * 4;
    int tc = (tid & 15) * 4;
    float acc[4][4] = {};
    const float* Abase = A + (size_t)(bm + lr)*K;
    const float* Wbase = W + (size_t)(bn + lr)*K;
    for (int k0 = 0; k0 < K; k0 += 16){
        float4 av = *(const float4*)(Abase + k0 + lk);
        float4 wv = *(const float4*)(Wbase + k0 + lk);
        __syncthreads();
        As[lk+0][lr]=av.x; As[lk+1][lr]=av.y; As[lk+2][lr]=av.z; As[lk+3][lr]=av.w;
        Ws[lk+0][lr]=wv.x; Ws[lk+1][lr]=wv.y; Ws[lk+2][lr]=wv.z; Ws[lk+3][lr]=wv.w;
        __syncthreads();
        #pragma unroll
        for (int kk = 0; kk < 16; kk++){
            float4 a = *(const float4*)&As[kk][tr];
            float4 w = *(const float4*)&Ws[kk][tc];
            acc[0][0] += a.x*w.x; acc[0][1] += a.x*w.y; acc[0][2] += a.x*w.z; acc[0][3] += a.x*w.w;
            acc[1][0] += a.y*w.x; acc[1][1] += a.y*w.y; acc[1][2] += a.y*w.z; acc[1][3] += a.y*w.w;
            acc[2][0] += a.z*w.x; acc[2][1] += a.z*w.y; acc[2][2] += a.z*w.z; acc[2][3] += a.z*w.w;
            acc[3][0] += a.w*w.x; acc[3][1] += a.w*w.y; acc[3][2] += a.w*w.z; acc[3][3] += a.w*w.w;
        }
    }
    #pragma unroll
    for (int i = 0; i < 4; i++){
        #pragma unroll
        for (int j = 0; j < 4; j++){
            float v = acc[i][j];
            if (bias) v += bias[bn + tc + j];
            if (ACT == 1) v = tanhf(v);
            C[(size_t)(bm + tr + i)*N + bn + tc + j] = v;
        }
    }
}

// ---------- batched bf16 MFMA GEMM, frag-ordered B (and optionally A) ----------
// 128x128 block tile, 4 waves (2x2), each wave 64x64. C row-major.
template<int AFRAG, int ACT, typename OutT>
__global__ __launch_bounds__(256) void k_gemmf(const u16* __restrict__ A, const u16* __restrict__ B,
                                               const float* __restrict__ bias, OutT* __restrict__ C,
                                               int M, int N, int K){
    int tid = threadIdx.x, lane = tid & 63, w = tid >> 6;
    int wm = w >> 1, wn = w & 1;
    int row0 = blockIdx.y*128 + wm*64, col0 = blockIdx.x*128 + wn*64;
    int r16 = lane & 15, kg8 = (lane >> 4)*8, rg = (lane >> 4)*4;
    int K32 = K >> 5;
    f32x4 acc[4][4] = {};
    for (int k0 = 0; k0 < K32; k0++){
        bf16x8 af[4], bfv[4];
        #pragma unroll
        for (int i = 0; i < 4; i++){
            if (AFRAG) af[i] = *(const bf16x8*)(A + (((size_t)((row0 >> 4) + i)*K32 + k0) << 9) + lane*8);
            else       af[i] = *(const bf16x8*)(A + (size_t)(row0 + i*16 + r16)*K + k0*32 + kg8);
        }
        #pragma unroll
        for (int j = 0; j < 4; j++)
            bfv[j] = *(const bf16x8*)(B + (((size_t)((col0 >> 4) + j)*K32 + k0) << 9) + lane*8);
        #pragma unroll
        for (int i = 0; i < 4; i++)
            #pragma unroll
            for (int j = 0; j < 4; j++)
                acc[i][j] = __builtin_amdgcn_mfma_f32_16x16x32_bf16(af[i], bfv[j], acc[i][j], 0, 0, 0);
    }
    #pragma unroll
    for (int i = 0; i < 4; i++){
        #pragma unroll
        for (int j = 0; j < 4; j++){
            #pragma unroll
            for (int r = 0; r < 4; r++){
                int row = row0 + i*16 + rg + r;
                int col = col0 + j*16 + r16;
                float v = acc[i][j][r];
                if (bias) v += bias[col];
                if (ACT) v = tanhf(v);
                stoval(C + (size_t)row*N + col, v);
            }
        }
    }
}

// ---------- fused final GEMM (frag A and B) + row-max (excl tgt) + s_true ----------
__global__ __launch_bounds__(256) void k_final(const u16* __restrict__ logitf, const u16* __restrict__ Wf,
                                               const int* __restrict__ y, float* __restrict__ pmax,
                                               float* __restrict__ strue){
    __shared__ float red[128][2];
    int tid = threadIdx.x, w = tid >> 6, lane = tid & 63;
    int wm = w >> 1, wn = w & 1;
    int row0 = blockIdx.x*128 + wm*64;
    int col0 = blockIdx.y*128 + wn*64;
    int r16 = lane & 15, rg = (lane >> 4)*4;
    f32x4 acc[4][4] = {};
    for (int k0 = 0; k0 < 16; k0++){
        bf16x8 af[4], bfv[4];
        #pragma unroll
        for (int i = 0; i < 4; i++)
            af[i] = *(const bf16x8*)(logitf + (((size_t)((row0 >> 4) + i)*16 + k0) << 9) + lane*8);
        #pragma unroll
        for (int j = 0; j < 4; j++)
            bfv[j] = *(const bf16x8*)(Wf + (((size_t)((col0 >> 4) + j)*16 + k0) << 9) + lane*8);
        #pragma unroll
        for (int i = 0; i < 4; i++)
            #pragma unroll
            for (int j = 0; j < 4; j++)
                acc[i][j] = __builtin_amdgcn_mfma_f32_16x16x32_bf16(af[i], bfv[j], acc[i][j], 0, 0, 0);
    }
    #pragma unroll
    for (int i = 0; i < 4; i++){
        #pragma unroll
        for (int r = 0; r < 4; r++){
            int row = row0 + i*16 + rg + r;
            int tgt = y[row + BB];
            float m = -1e30f;
            #pragma unroll
            for (int j = 0; j < 4; j++){
                float v = acc[i][j][r];
                int col = col0 + j*16 + r16;
                if (col == tgt){ strue[row] = v; v = -1e30f; }
                m = fmaxf(m, v);
            }
            m = fmaxf(m, __shfl_xor(m, 1));
            m = fmaxf(m, __shfl_xor(m, 2));
            m = fmaxf(m, __shfl_xor(m, 4));
            m = fmaxf(m, __shfl_xor(m, 8));
            if (r16 == 0) red[wm*64 + i*16 + rg + r][wn] = m;
        }
    }
    __syncthreads();
    if (tid < 128){
        float m = fmaxf(red[tid][0], red[tid][1]);
        pmax[(size_t)(blockIdx.x*128 + tid)*VCHUNKS + blockIdx.y] = m;
    }
}

__global__ __launch_bounds__(256) void k_loss(const float* __restrict__ pmax, const float* __restrict__ strue,
                                              const int* __restrict__ y, float* __restrict__ out){
    int R = blockIdx.x*256 + threadIdx.x;
    int lane = threadIdx.x & 63, wave = threadIdx.x >> 6;
    float l = 0.f;
    if (R < NROWS){
        int tgt = y[R + BB];
        if (tgt != 0){
            const float* pm = pmax + (size_t)R*VCHUNKS;
            float m = -1e30f;
            for (int i = 0; i < VCHUNKS; i++) m = fmaxf(m, pm[i]);
            l = fmaxf(FMARGIN - strue[R] + m, 0.f);
        }
    }
    #pragma unroll
    for (int off = 32; off; off >>= 1) l += __shfl_down(l, off);
    __shared__ float wsum[4];
    if (lane == 0) wsum[wave] = l;
    __syncthreads();
    if (threadIdx.x == 0) atomicAdd(out, wsum[0] + wsum[1] + wsum[2] + wsum[3]);
}

// ---------- persistent cooperative recurrence ----------
struct RA {
    const u16 *gi0, *Whh0, *Wcat, *Wih1, *ctxp, *h0b;
    const float *bih0, *bhh0, *bih1, *bhh1, *vatt, *mask, *ctx, *h0f;
    float *h1f, *proj, *gh1, *scoresv, *hA, *hB;
    u16 *h1b, *ztb, *h2all;
};

__global__ __launch_bounds__(256) void k_recur(RA a){
    cooperative_groups::grid_group grid = cooperative_groups::this_grid();
    __shared__ float alpha[SS];
    const int tid = threadIdx.x, lane = tid & 63, wv = tid >> 6;
    const int w = blockIdx.x*4 + wv;                 // 0..1023
    const int r16 = lane & 15, kg8 = (lane >> 4)*8, rg = (lane >> 4)*4;

    for (int t = 0; t < TP; t++){
        const u16*   hpb  = t ? (a.h2all + (size_t)(t-1)*BB*H) : a.h0b;
        const float* hpf  = t ? ((t & 1) ? a.hA : a.hB) : a.h0f;
        float*       h2f  = (t & 1) ? a.hB : a.hA;
        u16*         h2b  = a.h2all + (size_t)t*BB*H;

        // ---- P1: h1 = GRU0(gi0[t], hprev @ Whh0^T, hprev) ----
        if (w < 512){
            int rt = w >> 6, ct = w & 63;
            const u16* Ab = hpb + (size_t)(rt*16 + r16)*H + kg8;
            const u16* B0 = a.Whh0 + (size_t)(ct*32)*512 + lane*8;
            f32x4 ac0 = {}, ac1 = {}, ac2 = {};
            for (int k0 = 0; k0 < 32; k0++){
                bf16x8 av = *(const bf16x8*)(Ab + k0*32);
                bf16x8 b0 = *(const bf16x8*)(B0 + (size_t)k0*512);
                bf16x8 b1 = *(const bf16x8*)(B0 + (size_t)(64*32 + k0)*512);
                bf16x8 b2 = *(const bf16x8*)(B0 + (size_t)(128*32 + k0)*512);
                ac0 = __builtin_amdgcn_mfma_f32_16x16x32_bf16(av, b0, ac0, 0, 0, 0);
                ac1 = __builtin_amdgcn_mfma_f32_16x16x32_bf16(av, b1, ac1, 0, 0, 0);
                ac2 = __builtin_amdgcn_mfma_f32_16x16x32_bf16(av, b2, ac2, 0, 0, 0);
            }
            #pragma unroll
            for (int r = 0; r < 4; r++){
                int b = rt*16 + rg + r, j = ct*16 + r16;
                size_t gio = (size_t)(t*BB + b)*H3 + j;
                float gr = bf2f(a.gi0[gio])       + a.bih0[j];
                float gz = bf2f(a.gi0[gio +   H]) + a.bih0[H + j];
                float gn = bf2f(a.gi0[gio + 2*H]) + a.bih0[2*H + j];
                float hr = ac0[r] + a.bhh0[j];
                float hz = ac1[r] + a.bhh0[H + j];
                float hn = ac2[r] + a.bhh0[2*H + j];
                float rr = sigm(gr + hr), zz = sigm(gz + hz);
                float nn = tanhf(gn + rr*hn);
                float hv = (1.f - zz)*nn + zz*hpf[b*H + j];
                a.h1f[b*H + j] = hv;
                a.h1b[b*H + j] = f2bf(hv);
            }
        }
        grid.sync();

        // ---- P2: [proj | gh1] = h1 @ Wcat^T ----
        {
            int rt = w >> 7, ct2 = w & 127;
            const u16* Ab = a.h1b + (size_t)(rt*16 + r16)*H + kg8;
            const u16* Bb = a.Wcat + (size_t)(ct2*2*32)*512 + lane*8;
            f32x4 ac0 = {}, ac1 = {};
            for (int k0 = 0; k0 < 32; k0++){
                bf16x8 av = *(const bf16x8*)(Ab + k0*32);
                bf16x8 b0 = *(const bf16x8*)(Bb + (size_t)k0*512);
                bf16x8 b1 = *(const bf16x8*)(Bb + (size_t)(32 + k0)*512);
                ac0 = __builtin_amdgcn_mfma_f32_16x16x32_bf16(av, b0, ac0, 0, 0, 0);
                ac1 = __builtin_amdgcn_mfma_f32_16x16x32_bf16(av, b1, ac1, 0, 0, 0);
            }
            #pragma unroll
            for (int r = 0; r < 4; r++){
                int b = rt*16 + rg + r;
                int c0 = ct2*32 + r16, c1 = c0 + 16;
                if (c0 < H) a.proj[(size_t)b*H + c0] = ac0[r];
                else        a.gh1[(size_t)b*H3 + c0 - H] = ac0[r];
                if (c1 < H) a.proj[(size_t)b*H + c1] = ac1[r];
                else        a.gh1[(size_t)b*H3 + c1 - H] = ac1[r];
            }
        }
        grid.sync();

        // ---- P3a: scores[s,b] = tanh(ctxp[s,b,:] + proj[b,:]) . v_att ----
        #pragma unroll
        for (int q = 0; q < 8; q++){
            int idx = w*8 + q;
            int s = idx >> 7, b = idx & 127;
            const u16* cp = a.ctxp + ((size_t)(s*BB + b))*H + lane*16;
            const float* pj = a.proj + (size_t)b*H + lane*16;
            const float* vv = a.vatt + lane*16;
            float acc = 0.f;
            #pragma unroll
            for (int u = 0; u < 2; u++){
                u16x8 cv = *(const u16x8*)(cp + u*8);
                float4 p0 = *(const float4*)(pj + u*8);
                float4 p1 = *(const float4*)(pj + u*8 + 4);
                float4 v0 = *(const float4*)(vv + u*8);
                float4 v1 = *(const float4*)(vv + u*8 + 4);
                acc += tanhf(bf2f(cv[0]) + p0.x)*v0.x + tanhf(bf2f(cv[1]) + p0.y)*v0.y
                     + tanhf(bf2f(cv[2]) + p0.z)*v0.z + tanhf(bf2f(cv[3]) + p0.w)*v0.w
                     + tanhf(bf2f(cv[4]) + p1.x)*v1.x + tanhf(bf2f(cv[5]) + p1.y)*v1.y
                     + tanhf(bf2f(cv[6]) + p1.z)*v1.z + tanhf(bf2f(cv[7]) + p1.w)*v1.w;
            }
            #pragma unroll
            for (int off = 32; off; off >>= 1) acc += __shfl_xor(acc, off);
            if (lane == 0)
                a.scoresv[s*BB + b] = acc + ((a.mask[s*BB + b] > 0.f) ? 0.f : -1e9f);
        }
        grid.sync();

        // ---- P3b: softmax + z_t (bf16 row-major) ----
        {
            int b = blockIdx.x >> 1, half = blockIdx.x & 1;
            if (tid < 64){
                float v = a.scoresv[tid*BB + b];
                float m = v;
                #pragma unroll
                for (int off = 32; off; off >>= 1) m = fmaxf(m, __shfl_xor(m, off));
                float e = expf(v - m);
                float su = e;
                #pragma unroll
                for (int off = 32; off; off >>= 1) su += __shfl_xor(su, off);
                alpha[tid] = e / su;
            }
            __syncthreads();
            int c = half*512 + tid*2;
            float a0 = 0.f, a1 = 0.f;
            for (int s = 0; s < SS; s++){
                float al = alpha[s];
                float2 cv = *(const float2*)(a.ctx + ((size_t)(s*BB + b))*H + c);
                a0 += al*cv.x; a1 += al*cv.y;
            }
            unsigned pk = (unsigned)f2bf(a0) | ((unsigned)f2bf(a1) << 16);
            *(unsigned*)(a.ztb + (size_t)b*H + c) = pk;
            __syncthreads();
        }
        grid.sync();

        // ---- P4: h2 = GRU1(zt @ Wih1^T, gh1, h1) ----
        if (w < 512){
            int rt = w >> 6, ct = w & 63;
            const u16* Ab = a.ztb + (size_t)(rt*16 + r16)*H + kg8;
            const u16* B0 = a.Wih1 + (size_t)(ct*32)*512 + lane*8;
            f32x4 ac0 = {}, ac1 = {}, ac2 = {};
            for (int k0 = 0; k0 < 32; k0++){
                bf16x8 av = *(const bf16x8*)(Ab + k0*32);
                bf16x8 b0 = *(const bf16x8*)(B0 + (size_t)k0*512);
                bf16x8 b1 = *(const bf16x8*)(B0 + (size_t)(64*32 + k0)*512);
                bf16x8 b2 = *(const bf16x8*)(B0 + (size_t)(128*32 + k0)*512);
                ac0 = __builtin_amdgcn_mfma_f32_16x16x32_bf16(av, b0, ac0, 0, 0, 0);
                ac1 = __builtin_amdgcn_mfma_f32_16x16x32_bf16(av, b1, ac1, 0, 0, 0);
                ac2 = __builtin_amdgcn_mfma_f32_16x16x32_bf16(av, b2, ac2, 0, 0, 0);
            }
            #pragma unroll
            for (int r = 0; r < 4; r++){
                int b = rt*16 + rg + r, j = ct*16 + r16;
                size_t go = (size_t)b*H3 + j;
                float gr = ac0[r] + a.bih1[j];
                float gz = ac1[r] + a.bih1[H + j];
                float gn = ac2[r] + a.bih1[2*H + j];
                float hr = a.gh1[go]       + a.bhh1[j];
                float hz = a.gh1[go +   H] + a.bhh1[H + j];
                float hn = a.gh1[go + 2*H] + a.bhh1[2*H + j];
                float rr = sigm(gr + hr), zz = sigm(gz + hz);
                float nn = tanhf(gn + rr*hn);
                float hv = (1.f - zz)*nn + zz*a.h1f[b*H + j];
                h2f[b*H + j] = hv;
                h2b[b*H + j] = f2bf(hv);
            }
        }
        grid.sync();
    }
}

// ---------- launch ----------
extern "C" void kernel_launch(void* const* d_in, const int* in_sizes, int n_in,
                              void* d_out, int out_size, void* d_ws, size_t ws_size,
                              hipStream_t stream){
    const float* ctx    = (const float*)d_in[0];
    const float* mask   = (const float*)d_in[1];
    const int*   y      = (const int*)d_in[2];
    const float* emb_W  = (const float*)d_in[3];
    const float* W_init = (const float*)d_in[4];
    const float* b_init = (const float*)d_in[5];
    const float* W_ih0  = (const float*)d_in[6];
    const float* W_hh0  = (const float*)d_in[7];
    const float* b_ih0  = (const float*)d_in[8];
    const float* b_hh0  = (const float*)d_in[9];
    const float* W_c2c  = (const float*)d_in[10];
    const float* W_h2c  = (const float*)d_in[11];
    const float* v_att  = (const float*)d_in[12];
    const float* W_ih1  = (const float*)d_in[13];
    const float* W_hh1  = (const float*)d_in[14];
    const float* b_ih1  = (const float*)d_in[15];
    const float* b_hh1  = (const float*)d_in[16];
    const float* W_h2o  = (const float*)d_in[17];
    const float* b_h2o  = (const float*)d_in[18];
    const float* W_out  = (const float*)d_in[19];
    float* out = (float*)d_out;

    char* wsb = (char*)d_ws;
    size_t off = 0;
    auto alloc = [&](size_t bytes)->void*{
        void* p = (void*)(wsb + off);
        off = (off + bytes + 255) & ~(size_t)255;
        return p;
    };
    // frag-ordered weights
    u16* Wih0f = (u16*)alloc((size_t)H3*DIN*2);
    u16* Whh0f = (u16*)alloc((size_t)H3*H*2);
    u16* Wcatf = (u16*)alloc((size_t)4096*H*2);
    u16* Wih1f = (u16*)alloc((size_t)H3*H*2);
    u16* Wh2of = (u16*)alloc((size_t)DIN*H*2);
    u16* Wc2cf = (u16*)alloc((size_t)H*H*2);
    u16* Woutf = (u16*)alloc((size_t)VSZ*DIN*2);
    u16* ctxf  = (u16*)alloc((size_t)SS*BB*H*2);   // frag ctx; later reused as pmax (6 MB < 16.8 MB)
    u16* ctxpb = (u16*)alloc((size_t)SS*BB*H*2);   // row-major bf16 ctx_p
    u16* gi0b  = (u16*)alloc((size_t)NROWS*H3*2);  // row-major bf16; later reused as logitf f32 (12.3 MB < 37 MB)
    u16* embf  = (u16*)alloc((size_t)NROWS*DIN*2); // frag emb; later reused as logit frag (same size)
    u16* h2allb= (u16*)alloc((size_t)NROWS*H*2);
    float* strue  = (float*)alloc(NROWS*4);
    float* msum   = (float*)alloc(BB*4);
    float* meanc  = (float*)alloc((size_t)BB*H*4);
    float* h0f    = (float*)alloc((size_t)BB*H*4);
    u16*   h0b    = (u16*)alloc((size_t)BB*H*2);
    float* h1f    = (float*)alloc((size_t)BB*H*4);
    u16*   h1b    = (u16*)alloc((size_t)BB*H*2);
    float* projf  = (float*)alloc((size_t)BB*H*4);
    float* gh1f   = (float*)alloc((size_t)BB*H3*4);
    float* scoresv= (float*)alloc((size_t)SS*BB*4);
    float* hA     = (float*)alloc((size_t)BB*H*4);
    float* hB     = (float*)alloc((size_t)BB*H*4);
    u16*   ztb    = (u16*)alloc((size_t)BB*H*2);

    float* logitf  = (float*)gi0b;   // gi0 dead after recurrence
    u16*   logitfr = embf;           // emb frag dead after gi0 GEMM
    float* pmax    = (float*)ctxf;   // ctx frag dead after ctx_p GEMM

    hipMemsetAsync(d_out, 0, sizeof(float), stream);

    // ---- init: h0 + converts ----
    hipLaunchKernelGGL(k_mask_sum, dim3(1), dim3(128), 0, stream, mask, msum);
    hipLaunchKernelGGL(k_mean_ctx, dim3(BB*H/256), dim3(256), 0, stream, ctx, msum, meanc);
    hipLaunchKernelGGL((k_gemm_nt<1>), dim3(H/64, BB/64), dim3(256), 0, stream,
                       meanc, W_init, b_init, h0f, BB, H, H);
    hipLaunchKernelGGL(k_f32bf, dim3(BB*H/4/256), dim3(256), 0, stream, h0f, h0b, BB*H/4);

    hipLaunchKernelGGL(k_f2bf_frag, dim3(H3*DIN/8/256), dim3(256), 0, stream, W_ih0, Wih0f, H3*DIN/8, DIN/8);
    hipLaunchKernelGGL(k_f2bf_frag, dim3(H3*H/8/256), dim3(256), 0, stream, W_hh0, Whh0f, H3*H/8, H/8);
    hipLaunchKernelGGL(k_f2bf_frag, dim3(H*H/8/256), dim3(256), 0, stream, W_h2c, Wcatf, H*H/8, H/8);
    hipLaunchKernelGGL(k_f2bf_frag, dim3(H3*H/8/256), dim3(256), 0, stream, W_hh1, Wcatf + (size_t)64*32*512, H3*H/8, H/8);
    hipLaunchKernelGGL(k_f2bf_frag, dim3(H3*H/8/256), dim3(256), 0, stream, W_ih1, Wih1f, H3*H/8, H/8);
    hipLaunchKernelGGL(k_f2bf_frag, dim3(DIN*H/8/256), dim3(256), 0, stream, W_h2o, Wh2of, DIN*H/8, H/8);
    hipLaunchKernelGGL(k_f2bf_frag, dim3(H*H/8/256), dim3(256), 0, stream, W_c2c, Wc2cf, H*H/8, H/8);
    hipLaunchKernelGGL(k_f2bf_frag, dim3(SS*BB*H/8/256), dim3(256), 0, stream, ctx, ctxf, SS*BB*H/8, H/8);
    hipLaunchKernelGGL(k_rownorm_frag, dim3(VSZ/4), dim3(256), 0, stream, W_out, Woutf, VSZ);
    hipLaunchKernelGGL(k_emb_frag, dim3(NROWS/4), dim3(256), 0, stream, emb_W, y, embf);

    // ---- batched GEMMs ----
    hipLaunchKernelGGL((k_gemmf<1,0,u16>), dim3(H3/128, NROWS/128), dim3(256), 0, stream,
                       embf, Wih0f, (const float*)nullptr, gi0b, NROWS, H3, DIN);
    hipLaunchKernelGGL((k_gemmf<1,0,u16>), dim3(H/128, SS*BB/128), dim3(256), 0, stream,
                       ctxf, Wc2cf, (const float*)nullptr, ctxpb, SS*BB, H, H);

    // ---- persistent cooperative recurrence ----
    RA ra;
    ra.gi0 = gi0b; ra.Whh0 = Whh0f; ra.Wcat = Wcatf; ra.Wih1 = Wih1f;
    ra.ctxp = ctxpb; ra.h0b = h0b;
    ra.bih0 = b_ih0; ra.bhh0 = b_hh0; ra.bih1 = b_ih1; ra.bhh1 = b_hh1;
    ra.vatt = v_att; ra.mask = mask; ra.ctx = ctx; ra.h0f = h0f;
    ra.h1f = h1f; ra.proj = projf; ra.gh1 = gh1f; ra.scoresv = scoresv;
    ra.hA = hA; ra.hB = hB;
    ra.h1b = h1b; ra.ztb = ztb; ra.h2all = h2allb;
    void* kp[] = { (void*)&ra };
    hipLaunchCooperativeKernel((const void*)k_recur, dim3(256), dim3(256), kp, 0, stream);

    // ---- output head ----
    hipLaunchKernelGGL((k_gemmf<0,1,float>), dim3(DIN/128, NROWS/128), dim3(256), 0, stream,
                       h2allb, Wh2of, b_h2o, logitf, NROWS, DIN, H);
    hipLaunchKernelGGL(k_rownorm_frag, dim3(NROWS/4), dim3(256), 0, stream, logitf, logitfr, NROWS);
    hipLaunchKernelGGL(k_final, dim3(NROWS/128, VSZ/128), dim3(256), 0, stream,
                       logitfr, Woutf, y, pmax, strue);
    hipLaunchKernelGGL(k_loss, dim3((NROWS + 255)/256), dim3(256), 0, stream, pmax, strue, y, out);
}

// Round 5
// 10819.818 us; speedup vs baseline: 1.1405x; 1.1405x over previous
//
#include <hip/hip_runtime.h>
#include <math.h>

#define H    1024
#define H3   3072
#define DIN  512
#define VSZ  32000
#define SS   64
#define BB   128
#define TP   47
#define NROWS (TP*BB)      // 6016
#define VCHUNKS 250        // 32000 / 128
#define FMARGIN 0.1f

typedef unsigned short u16;
typedef __bf16 bf16_t;
typedef bf16_t bf16x8 __attribute__((ext_vector_type(8)));
typedef float f32x4 __attribute__((ext_vector_type(4)));
typedef u16 u16x4 __attribute__((ext_vector_type(4)));
typedef u16 u16x8 __attribute__((ext_vector_type(8)));

#define MFMA __builtin_amdgcn_mfma_f32_16x16x32_bf16

__device__ inline u16 f2bf(float f){
    unsigned b = __float_as_uint(f);
    return (u16)((b + 0x7FFFu + ((b >> 16) & 1u)) >> 16);
}
__device__ inline float bf2f(u16 u){ return __uint_as_float(((unsigned)u) << 16); }
__device__ inline float sigm(float x){ return 1.f/(1.f + expf(-x)); }

__device__ inline void stoval(float* p, float v){ *p = v; }
__device__ inline void stoval(u16* p, float v){ *p = f2bf(v); }

// ---------- small helpers ----------

__global__ __launch_bounds__(128) void k_mask_sum(const float* __restrict__ mask, float* __restrict__ msum){
    int b = threadIdx.x;
    if (b < BB){ float s = 0.f; for (int i = 0; i < SS; i++) s += mask[i*BB + b]; msum[b] = s; }
}

__global__ __launch_bounds__(256) void k_mean_ctx(const float* __restrict__ ctx, const float* __restrict__ msum,
                                                  float* __restrict__ mean){
    int idx = blockIdx.x*256 + threadIdx.x;
    if (idx < BB*H){
        float s = 0.f;
        for (int i = 0; i < SS; i++) s += ctx[(size_t)i*BB*H + idx];
        mean[idx] = s / msum[idx / H];
    }
}

// f32 row-major -> bf16 hi + lo row-major (hi+lo ~= f32)
__global__ __launch_bounds__(256) void k_split_hl(const float* __restrict__ in, u16* __restrict__ hi,
                                                  u16* __restrict__ lo, int n4){
    int i = blockIdx.x*256 + threadIdx.x;
    if (i >= n4) return;
    float4 v = ((const float4*)in)[i];
    u16x4 oh, ol;
    oh[0]=f2bf(v.x); ol[0]=f2bf(v.x - bf2f(oh[0]));
    oh[1]=f2bf(v.y); ol[1]=f2bf(v.y - bf2f(oh[1]));
    oh[2]=f2bf(v.z); ol[2]=f2bf(v.z - bf2f(oh[2]));
    oh[3]=f2bf(v.w); ol[3]=f2bf(v.w - bf2f(oh[3]));
    ((u16x4*)hi)[i] = oh; ((u16x4*)lo)[i] = ol;
}

// row-major f32 (R x K) -> MFMA-fragment-ordered bf16: [rt][k0][lane][8]
__global__ __launch_bounds__(256) void k_f2bf_frag(const float* __restrict__ in, u16* __restrict__ out,
                                                   int RK8, int K8){
    int t = blockIdx.x*256 + threadIdx.x;
    if (t >= RK8) return;
    int r = t / K8, k8 = t - r*K8;
    const float* p = in + (size_t)r*K8*8 + k8*8;
    float4 a = *(const float4*)p;
    float4 b = *(const float4*)(p + 4);
    size_t dst = ((size_t)(r >> 4)*(K8 >> 2) + (k8 >> 2))*512 + (size_t)((r & 15) + (k8 & 3)*16)*8;
    u16x8 o;
    o[0]=f2bf(a.x); o[1]=f2bf(a.y); o[2]=f2bf(a.z); o[3]=f2bf(a.w);
    o[4]=f2bf(b.x); o[5]=f2bf(b.y); o[6]=f2bf(b.z); o[7]=f2bf(b.w);
    *(u16x8*)(out + dst) = o;
}

// 1024x1024 f32 [j][k] -> bf16 transposed [k][j]
__global__ __launch_bounds__(256) void k_transp_bf(const float* __restrict__ in, u16* __restrict__ out){
    __shared__ float t[32][33];
    int tx = threadIdx.x & 31, tg = (threadIdx.x >> 5)*4;
    int jb = blockIdx.y*32, kb = blockIdx.x*32;
    #pragma unroll
    for (int r = 0; r < 4; r++)
        t[tg + r][tx] = in[(size_t)(jb + tg + r)*1024 + kb + tx];
    __syncthreads();
    #pragma unroll
    for (int r = 0; r < 4; r++)
        out[(size_t)(kb + tg + r)*1024 + jb + tx] = f2bf(t[tx][tg + r]);
}

// rows of 512 f32: L2-normalize -> frag-ordered bf16 (K=512)
__global__ __launch_bounds__(256) void k_rownorm_frag(const float* __restrict__ in, u16* __restrict__ out,
                                                      int nrows){
    int w = threadIdx.x >> 6, lane = threadIdx.x & 63;
    int row = blockIdx.x*4 + w;
    if (row >= nrows) return;
    const float* r = in + (size_t)row*512 + lane*8;
    float4 a = *(const float4*)r;
    float4 b = *(const float4*)(r + 4);
    float s = a.x*a.x + a.y*a.y + a.z*a.z + a.w*a.w
            + b.x*b.x + b.y*b.y + b.z*b.z + b.w*b.w;
    #pragma unroll
    for (int off = 32; off; off >>= 1) s += __shfl_xor(s, off);
    float inv = rsqrtf(s);
    size_t dst = ((size_t)(row >> 4)*16 + (lane >> 2))*512 + (size_t)((row & 15) + (lane & 3)*16)*8;
    u16x8 o;
    o[0]=f2bf(a.x*inv); o[1]=f2bf(a.y*inv); o[2]=f2bf(a.z*inv); o[3]=f2bf(a.w*inv);
    o[4]=f2bf(b.x*inv); o[5]=f2bf(b.y*inv); o[6]=f2bf(b.z*inv); o[7]=f2bf(b.w*inv);
    *(u16x8*)(out + dst) = o;
}

// gather emb_W[y[row]] -> frag-ordered bf16 hi/lo (K=512)
__global__ __launch_bounds__(256) void k_emb_frag_hl(const float* __restrict__ emb, const int* __restrict__ y,
                                                     u16* __restrict__ ohi, u16* __restrict__ olo){
    int w = threadIdx.x >> 6, lane = threadIdx.x & 63;
    int row = blockIdx.x*4 + w;            // < 6016
    int src = y[row];
    const float* r = emb + (size_t)src*512 + lane*8;
    float4 a = *(const float4*)r;
    float4 b = *(const float4*)(r + 4);
    size_t dst = ((size_t)(row >> 4)*16 + (lane >> 2))*512 + (size_t)((row & 15) + (lane & 3)*16)*8;
    float v[8] = {a.x,a.y,a.z,a.w,b.x,b.y,b.z,b.w};
    u16x8 oh, ol;
    #pragma unroll
    for (int e = 0; e < 8; e++){ oh[e] = f2bf(v[e]); ol[e] = f2bf(v[e] - bf2f(oh[e])); }
    *(u16x8*)(ohi + dst) = oh;
    *(u16x8*)(olo + dst) = ol;
}

// ---------- fp32 GEMM (h0 init only) ----------
template<int ACT>
__global__ __launch_bounds__(256) void k_gemm_nt(const float* __restrict__ A, const float* __restrict__ W,
                                                 const float* __restrict__ bias, float* __restrict__ C,
                                                 int M, int N, int K){
    __shared__ float As[16][68];
    __shared__ float Ws[16][68];
    int tid = threadIdx.x;
    int bm = blockIdx.y*64, bn = blockIdx.x*64;
    int lr = tid >> 2;
    int lk = (tid & 3) * 4;
    int tr = (tid >> 4) * 4;
    int tc = (tid & 15) * 4;
    float acc[4][4] = {};
    const float* Abase = A + (size_t)(bm + lr)*K;
    const float* Wbase = W + (size_t)(bn + lr)*K;
    for (int k0 = 0; k0 < K; k0 += 16){
        float4 av = *(const float4*)(Abase + k0 + lk);
        float4 wv = *(const float4*)(Wbase + k0 + lk);
        __syncthreads();
        As[lk+0][lr]=av.x; As[lk+1][lr]=av.y; As[lk+2][lr]=av.z; As[lk+3][lr]=av.w;
        Ws[lk+0][lr]=wv.x; Ws[lk+1][lr]=wv.y; Ws[lk+2][lr]=wv.z; Ws[lk+3][lr]=wv.w;
        __syncthreads();
        #pragma unroll
        for (int kk = 0; kk < 16; kk++){
            float4 a = *(const float4*)&As[kk][tr];
            float4 w = *(const float4*)&Ws[kk][tc];
            acc[0][0] += a.x*w.x; acc[0][1] += a.x*w.y; acc[0][2] += a.x*w.z; acc[0][3] += a.x*w.w;
            acc[1][0] += a.y*w.x; acc[1][1] += a.y*w.y; acc[1][2] += a.y*w.z; acc[1][3] += a.y*w.w;
            acc[2][0] += a.z*w.x; acc[2][1] += a.z*w.y; acc[2][2] += a.z*w.z; acc[2][3] += a.z*w.w;
            acc[3][0] += a.w*w.x; acc[3][1] += a.w*w.y; acc[3][2] += a.w*w.z; acc[3][3] += a.w*w.w;
        }
    }
    #pragma unroll
    for (int i = 0; i < 4; i++){
        #pragma unroll
        for (int j = 0; j < 4; j++){
            float v = acc[i][j];
            if (bias) v += bias[bn + tc + j];
            if (ACT == 1) v = tanhf(v);
            C[(size_t)(bm + tr + i)*N + bn + tc + j] = v;
        }
    }
}

// ---------- batched bf16 MFMA GEMM (frag B; A frag or row-major; optional hi/lo A split) ----------
template<int AFRAG, int ASPLIT, int ACT, typename OutT>
__global__ __launch_bounds__(256) void k_gemmf(const u16* __restrict__ A, const u16* __restrict__ Alo,
                                               const u16* __restrict__ B, const float* __restrict__ bias,
                                               OutT* __restrict__ C, int M, int N, int K){
    int tid = threadIdx.x, lane = tid & 63, w = tid >> 6;
    int wm = w >> 1, wn = w & 1;
    int row0 = blockIdx.y*128 + wm*64, col0 = blockIdx.x*128 + wn*64;
    int r16 = lane & 15, kg8 = (lane >> 4)*8, rg = (lane >> 4)*4;
    int K32 = K >> 5;
    f32x4 acc[4][4] = {};
    for (int k0 = 0; k0 < K32; k0++){
        bf16x8 af[4], afl[4], bfv[4];
        #pragma unroll
        for (int i = 0; i < 4; i++){
            if (AFRAG){
                af[i] = *(const bf16x8*)(A + (((size_t)((row0 >> 4) + i)*K32 + k0) << 9) + lane*8);
                if (ASPLIT) afl[i] = *(const bf16x8*)(Alo + (((size_t)((row0 >> 4) + i)*K32 + k0) << 9) + lane*8);
            } else {
                af[i] = *(const bf16x8*)(A + (size_t)(row0 + i*16 + r16)*K + k0*32 + kg8);
                if (ASPLIT) afl[i] = *(const bf16x8*)(Alo + (size_t)(row0 + i*16 + r16)*K + k0*32 + kg8);
            }
        }
        #pragma unroll
        for (int j = 0; j < 4; j++)
            bfv[j] = *(const bf16x8*)(B + (((size_t)((col0 >> 4) + j)*K32 + k0) << 9) + lane*8);
        #pragma unroll
        for (int i = 0; i < 4; i++)
            #pragma unroll
            for (int j = 0; j < 4; j++){
                acc[i][j] = MFMA(af[i], bfv[j], acc[i][j], 0, 0, 0);
                if (ASPLIT) acc[i][j] = MFMA(afl[i], bfv[j], acc[i][j], 0, 0, 0);
            }
    }
    #pragma unroll
    for (int i = 0; i < 4; i++){
        #pragma unroll
        for (int j = 0; j < 4; j++){
            #pragma unroll
            for (int r = 0; r < 4; r++){
                int row = row0 + i*16 + rg + r;
                int col = col0 + j*16 + r16;
                float v = acc[i][j][r];
                if (bias) v += bias[col];
                if (ACT) v = tanhf(v);
                stoval(C + (size_t)row*N + col, v);
            }
        }
    }
}

// ---------- per-step kernel A: GRU0 ----------
__global__ __launch_bounds__(256) void kA_gru0(const u16* __restrict__ hphi, const u16* __restrict__ hplo,
                                               const float* __restrict__ hpf, const u16* __restrict__ Whh0f,
                                               const u16* __restrict__ gi0t, const float* __restrict__ bhh0,
                                               float* __restrict__ h1f, u16* __restrict__ h1hi,
                                               u16* __restrict__ h1lo){
    int tid = threadIdx.x, lane = tid & 63, wv = tid >> 6;
    int w = blockIdx.x*4 + wv;
    int rt = w & 7, ct = w >> 3;
    int r16 = lane & 15, kg8 = (lane >> 4)*8, rg = (lane >> 4)*4;
    const u16* Ah = hphi + (size_t)(rt*16 + r16)*H + kg8;
    const u16* Al = hplo + (size_t)(rt*16 + r16)*H + kg8;
    const u16* B0 = Whh0f + (size_t)(ct*32)*512 + lane*8;
    f32x4 ac0 = {}, ac1 = {}, ac2 = {};
    for (int k0 = 0; k0 < 32; k0++){
        bf16x8 ah = *(const bf16x8*)(Ah + k0*32);
        bf16x8 al = *(const bf16x8*)(Al + k0*32);
        bf16x8 b0 = *(const bf16x8*)(B0 + (size_t)k0*512);
        bf16x8 b1 = *(const bf16x8*)(B0 + (size_t)(64*32 + k0)*512);
        bf16x8 b2 = *(const bf16x8*)(B0 + (size_t)(128*32 + k0)*512);
        ac0 = MFMA(ah, b0, ac0, 0, 0, 0); ac0 = MFMA(al, b0, ac0, 0, 0, 0);
        ac1 = MFMA(ah, b1, ac1, 0, 0, 0); ac1 = MFMA(al, b1, ac1, 0, 0, 0);
        ac2 = MFMA(ah, b2, ac2, 0, 0, 0); ac2 = MFMA(al, b2, ac2, 0, 0, 0);
    }
    #pragma unroll
    for (int r = 0; r < 4; r++){
        int b = rt*16 + rg + r, j = ct*16 + r16;
        size_t gio = (size_t)b*H3 + j;
        float gr = bf2f(gi0t[gio]);          // bias b_ih0 pre-added in batched GEMM
        float gz = bf2f(gi0t[gio + H]);
        float gn = bf2f(gi0t[gio + 2*H]);
        float hr = ac0[r] + bhh0[j];
        float hz = ac1[r] + bhh0[H + j];
        float hn = ac2[r] + bhh0[2*H + j];
        float rr = sigm(gr + hr), zz = sigm(gz + hz);
        float nn = tanhf(gn + rr*hn);
        float hv = (1.f - zz)*nn + zz*hpf[b*H + j];
        h1f[b*H + j] = hv;
        u16 hi = f2bf(hv);
        h1hi[b*H + j] = hi;
        h1lo[b*H + j] = f2bf(hv - bf2f(hi));
    }
}

// ---------- per-step kernel B: fused attention (one block per batch b) ----------
__global__ __launch_bounds__(256) void kB_attn(const float* __restrict__ h1f, const u16* __restrict__ WT,
                                               const u16* __restrict__ ctxp, const float* __restrict__ vatt,
                                               const float* __restrict__ mask, const float* __restrict__ ctx,
                                               u16* __restrict__ zthi, u16* __restrict__ ztlo){
    __shared__ float hs[H];
    __shared__ float ps[H];
    __shared__ float sal[SS];
    int b = blockIdx.x, tid = threadIdx.x, lane = tid & 63, wv = tid >> 6;
    ((float4*)hs)[tid] = ((const float4*)(h1f + (size_t)b*H))[tid];
    __syncthreads();
    // proj[j] = sum_k h1[k] * W_h2c[j][k]  via transposed WT[k][j] (coalesced)
    float p0 = 0.f, p1 = 0.f, p2 = 0.f, p3 = 0.f;
    #pragma unroll 4
    for (int k = 0; k < H; k++){
        u16x4 wv4 = *(const u16x4*)(WT + (size_t)k*H + tid*4);
        float hk = hs[k];
        p0 += hk*bf2f(wv4[0]); p1 += hk*bf2f(wv4[1]); p2 += hk*bf2f(wv4[2]); p3 += hk*bf2f(wv4[3]);
    }
    ps[tid*4+0] = p0; ps[tid*4+1] = p1; ps[tid*4+2] = p2; ps[tid*4+3] = p3;
    __syncthreads();
    // scores: wave wv handles s = wv*16 + q
    for (int q = 0; q < 16; q++){
        int s = wv*16 + q;
        const u16* cp = ctxp + ((size_t)(s*BB + b))*H;
        float acc = 0.f;
        #pragma unroll
        for (int u = 0; u < 16; u++){
            int hh = u*64 + lane;
            acc += tanhf(bf2f(cp[hh]) + ps[hh]) * vatt[hh];
        }
        #pragma unroll
        for (int off = 32; off; off >>= 1) acc += __shfl_xor(acc, off);
        if (lane == 0) sal[s] = acc + ((mask[s*BB + b] > 0.f) ? 0.f : -1e9f);
    }
    __syncthreads();
    if (tid < 64){
        float v = sal[tid];
        float m = v;
        #pragma unroll
        for (int off = 32; off; off >>= 1) m = fmaxf(m, __shfl_xor(m, off));
        float e = expf(v - m);
        float su = e;
        #pragma unroll
        for (int off = 32; off; off >>= 1) su += __shfl_xor(su, off);
        sal[tid] = e / su;
    }
    __syncthreads();
    // z_t
    float za0 = 0.f, za1 = 0.f, za2 = 0.f, za3 = 0.f;
    for (int s = 0; s < SS; s++){
        float al = sal[s];
        float4 cv = *(const float4*)(ctx + ((size_t)(s*BB + b))*H + tid*4);
        za0 += al*cv.x; za1 += al*cv.y; za2 += al*cv.z; za3 += al*cv.w;
    }
    u16x4 zh, zl;
    zh[0]=f2bf(za0); zl[0]=f2bf(za0 - bf2f(zh[0]));
    zh[1]=f2bf(za1); zl[1]=f2bf(za1 - bf2f(zh[1]));
    zh[2]=f2bf(za2); zl[2]=f2bf(za2 - bf2f(zh[2]));
    zh[3]=f2bf(za3); zl[3]=f2bf(za3 - bf2f(zh[3]));
    *(u16x4*)(zthi + (size_t)b*H + tid*4) = zh;
    *(u16x4*)(ztlo + (size_t)b*H + tid*4) = zl;
}

// ---------- per-step kernel C: GRU1 (dual GEMM gi1 + gh1 in-wave) ----------
__global__ __launch_bounds__(256) void kC_gru1(const u16* __restrict__ zthi, const u16* __restrict__ ztlo,
                                               const u16* __restrict__ h1hi, const u16* __restrict__ h1lo,
                                               const float* __restrict__ h1f, const u16* __restrict__ Wih1f,
                                               const u16* __restrict__ Whh1f, const float* __restrict__ bih1,
                                               const float* __restrict__ bhh1, float* __restrict__ h2f,
                                               u16* __restrict__ h2hi, u16* __restrict__ h2lo){
    int tid = threadIdx.x, lane = tid & 63, wv = tid >> 6;
    int w = blockIdx.x*4 + wv;
    int rt = w & 7, ct = w >> 3;
    int r16 = lane & 15, kg8 = (lane >> 4)*8, rg = (lane >> 4)*4;
    const u16* Zh = zthi + (size_t)(rt*16 + r16)*H + kg8;
    const u16* Zl = ztlo + (size_t)(rt*16 + r16)*H + kg8;
    const u16* Ah = h1hi + (size_t)(rt*16 + r16)*H + kg8;
    const u16* Al = h1lo + (size_t)(rt*16 + r16)*H + kg8;
    const u16* Bi = Wih1f + (size_t)(ct*32)*512 + lane*8;
    const u16* Bh = Whh1f + (size_t)(ct*32)*512 + lane*8;
    f32x4 ai0 = {}, ai1 = {}, ai2 = {}, ah0 = {}, ah1 = {}, ah2 = {};
    for (int k0 = 0; k0 < 32; k0++){
        bf16x8 zh = *(const bf16x8*)(Zh + k0*32);
        bf16x8 zl = *(const bf16x8*)(Zl + k0*32);
        bf16x8 xh = *(const bf16x8*)(Ah + k0*32);
        bf16x8 xl = *(const bf16x8*)(Al + k0*32);
        bf16x8 bi0 = *(const bf16x8*)(Bi + (size_t)k0*512);
        bf16x8 bi1 = *(const bf16x8*)(Bi + (size_t)(64*32 + k0)*512);
        bf16x8 bi2 = *(const bf16x8*)(Bi + (size_t)(128*32 + k0)*512);
        bf16x8 bh0 = *(const bf16x8*)(Bh + (size_t)k0*512);
        bf16x8 bh1 = *(const bf16x8*)(Bh + (size_t)(64*32 + k0)*512);
        bf16x8 bh2 = *(const bf16x8*)(Bh + (size_t)(128*32 + k0)*512);
        ai0 = MFMA(zh, bi0, ai0, 0, 0, 0); ai0 = MFMA(zl, bi0, ai0, 0, 0, 0);
        ai1 = MFMA(zh, bi1, ai1, 0, 0, 0); ai1 = MFMA(zl, bi1, ai1, 0, 0, 0);
        ai2 = MFMA(zh, bi2, ai2, 0, 0, 0); ai2 = MFMA(zl, bi2, ai2, 0, 0, 0);
        ah0 = MFMA(xh, bh0, ah0, 0, 0, 0); ah0 = MFMA(xl, bh0, ah0, 0, 0, 0);
        ah1 = MFMA(xh, bh1, ah1, 0, 0, 0); ah1 = MFMA(xl, bh1, ah1, 0, 0, 0);
        ah2 = MFMA(xh, bh2, ah2, 0, 0, 0); ah2 = MFMA(xl, bh2, ah2, 0, 0, 0);
    }
    #pragma unroll
    for (int r = 0; r < 4; r++){
        int b = rt*16 + rg + r, j = ct*16 + r16;
        float gr = ai0[r] + bih1[j];
        float gz = ai1[r] + bih1[H + j];
        float gn = ai2[r] + bih1[2*H + j];
        float hr = ah0[r] + bhh1[j];
        float hz = ah1[r] + bhh1[H + j];
        float hn = ah2[r] + bhh1[2*H + j];
        float rr = sigm(gr + hr), zz = sigm(gz + hz);
        float nn = tanhf(gn + rr*hn);
        float hv = (1.f - zz)*nn + zz*h1f[b*H + j];
        h2f[b*H + j] = hv;
        u16 hi = f2bf(hv);
        h2hi[b*H + j] = hi;
        h2lo[b*H + j] = f2bf(hv - bf2f(hi));
    }
}

// ---------- fused final GEMM (frag A and B) + row-max (excl tgt) + s_true ----------
__global__ __launch_bounds__(256) void k_final(const u16* __restrict__ logitf, const u16* __restrict__ Wf,
                                               const int* __restrict__ y, float* __restrict__ pmax,
                                               float* __restrict__ strue){
    __shared__ float red[128][2];
    int tid = threadIdx.x, w = tid >> 6, lane = tid & 63;
    int wm = w >> 1, wn = w & 1;
    int row0 = blockIdx.x*128 + wm*64;
    int col0 = blockIdx.y*128 + wn*64;
    int r16 = lane & 15, rg = (lane >> 4)*4;
    f32x4 acc[4][4] = {};
    for (int k0 = 0; k0 < 16; k0++){
        bf16x8 af[4], bfv[4];
        #pragma unroll
        for (int i = 0; i < 4; i++)
            af[i] = *(const bf16x8*)(logitf + (((size_t)((row0 >> 4) + i)*16 + k0) << 9) + lane*8);
        #pragma unroll
        for (int j = 0; j < 4; j++)
            bfv[j] = *(const bf16x8*)(Wf + (((size_t)((col0 >> 4) + j)*16 + k0) << 9) + lane*8);
        #pragma unroll
        for (int i = 0; i < 4; i++)
            #pragma unroll
            for (int j = 0; j < 4; j++)
                acc[i][j] = MFMA(af[i], bfv[j], acc[i][j], 0, 0, 0);
    }
    #pragma unroll
    for (int i = 0; i < 4; i++){
        #pragma unroll
        for (int r = 0; r < 4; r++){
            int row = row0 + i*16 + rg + r;
            int tgt = y[row + BB];
            float m = -1e30f;
            #pragma unroll
            for (int j = 0; j < 4; j++){
                float v = acc[i][j][r];
                int col = col0 + j*16 + r16;
                if (col == tgt){ strue[row] = v; v = -1e30f; }
                m = fmaxf(m, v);
            }
            m = fmaxf(m, __shfl_xor(m, 1));
            m = fmaxf(m, __shfl_xor(m, 2));
            m = fmaxf(m, __shfl_xor(m, 4));
            m = fmaxf(m, __shfl_xor(m, 8));
            if (r16 == 0) red[wm*64 + i*16 + rg + r][wn] = m;
        }
    }
    __syncthreads();
    if (tid < 128){
        float m = fmaxf(red[tid][0], red[tid][1]);
        pmax[(size_t)(blockIdx.x*128 + tid)*VCHUNKS + blockIdx.y] = m;
    }
}

__global__ __launch_bounds__(256) void k_loss(const float* __restrict__ pmax, const float* __restrict__ strue,
                                              const int* __restrict__ y, float* __restrict__ out){
    int R = blockIdx.x*256 + threadIdx.x;
    int lane = threadIdx.x & 63, wave = threadIdx.x >> 6;
    float l = 0.f;
    if (R < NROWS){
        int tgt = y[R + BB];
        if (tgt != 0){
            const float* pm = pmax + (size_t)R*VCHUNKS;
            float m = -1e30f;
            for (int i = 0; i < VCHUNKS; i++) m = fmaxf(m, pm[i]);
            l = fmaxf(FMARGIN - strue[R] + m, 0.f);
        }
    }
    #pragma unroll
    for (int off = 32; off; off >>= 1) l += __shfl_down(l, off);
    __shared__ float wsum[4];
    if (lane == 0) wsum[wave] = l;
    __syncthreads();
    if (threadIdx.x == 0) atomicAdd(out, wsum[0] + wsum[1] + wsum[2] + wsum[3]);
}

// ---------- launch ----------
extern "C" void kernel_launch(void* const* d_in, const int* in_sizes, int n_in,
                              void* d_out, int out_size, void* d_ws, size_t ws_size,
                              hipStream_t stream){
    const float* ctx    = (const float*)d_in[0];
    const float* mask   = (const float*)d_in[1];
    const int*   y      = (const int*)d_in[2];
    const float* emb_W  = (const float*)d_in[3];
    const float* W_init = (const float*)d_in[4];
    const float* b_init = (const float*)d_in[5];
    const float* W_ih0  = (const float*)d_in[6];
    const float* W_hh0  = (const float*)d_in[7];
    const float* b_ih0  = (const float*)d_in[8];
    const float* b_hh0  = (const float*)d_in[9];
    const float* W_c2c  = (const float*)d_in[10];
    const float* W_h2c  = (const float*)d_in[11];
    const float* v_att  = (const float*)d_in[12];
    const float* W_ih1  = (const float*)d_in[13];
    const float* W_hh1  = (const float*)d_in[14];
    const float* b_ih1  = (const float*)d_in[15];
    const float* b_hh1  = (const float*)d_in[16];
    const float* W_h2o  = (const float*)d_in[17];
    const float* b_h2o  = (const float*)d_in[18];
    const float* W_out  = (const float*)d_in[19];
    float* out = (float*)d_out;

    char* wsb = (char*)d_ws;
    size_t off = 0;
    auto alloc = [&](size_t bytes)->void*{
        void* p = (void*)(wsb + off);
        off = (off + bytes + 255) & ~(size_t)255;
        return p;
    };
    u16* Wih0f = (u16*)alloc((size_t)H3*DIN*2);
    u16* Whh0f = (u16*)alloc((size_t)H3*H*2);
    u16* Wih1f = (u16*)alloc((size_t)H3*H*2);
    u16* Whh1f = (u16*)alloc((size_t)H3*H*2);
    u16* Wh2of = (u16*)alloc((size_t)DIN*H*2);
    u16* Wc2cf = (u16*)alloc((size_t)H*H*2);
    u16* WTh2c = (u16*)alloc((size_t)H*H*2);
    u16* Woutf = (u16*)alloc((size_t)VSZ*DIN*2);
    u16* ctxf  = (u16*)alloc((size_t)SS*BB*H*2);   // -> pmax alias (6.0MB <= 16.8MB)
    u16* ctxpb = (u16*)alloc((size_t)SS*BB*H*2);   // -> logitf alias (12.3MB <= 16.8MB)
    u16* gi0b  = (u16*)alloc((size_t)NROWS*H3*2);
    u16* embfh = (u16*)alloc((size_t)NROWS*DIN*2); // -> logitfr alias (same size)
    u16* embfl = (u16*)alloc((size_t)NROWS*DIN*2);
    u16* h2allb= (u16*)alloc((size_t)NROWS*H*2);   // bf16-hi h2 trajectory
    float* strue  = (float*)alloc(NROWS*4);
    float* msum   = (float*)alloc(BB*4);
    float* meanc  = (float*)alloc((size_t)BB*H*4);
    float* h0f    = (float*)alloc((size_t)BB*H*4);
    u16*   h0hi   = (u16*)alloc((size_t)BB*H*2);
    u16*   h0lo   = (u16*)alloc((size_t)BB*H*2);
    float* h1f    = (float*)alloc((size_t)BB*H*4);
    u16*   h1hi   = (u16*)alloc((size_t)BB*H*2);
    u16*   h1lo   = (u16*)alloc((size_t)BB*H*2);
    u16*   zthi   = (u16*)alloc((size_t)BB*H*2);
    u16*   ztlo   = (u16*)alloc((size_t)BB*H*2);
    float* hA     = (float*)alloc((size_t)BB*H*4);
    float* hB     = (float*)alloc((size_t)BB*H*4);
    u16*   hloA   = (u16*)alloc((size_t)BB*H*2);
    u16*   hloB   = (u16*)alloc((size_t)BB*H*2);

    float* logitf  = (float*)ctxpb;  // dead after recurrence
    u16*   logitfr = embfh;          // dead after gi0 GEMM
    float* pmax    = (float*)ctxf;   // dead after ctx_p GEMM

    hipMemsetAsync(d_out, 0, sizeof(float), stream);

    // ---- init ----
    hipLaunchKernelGGL(k_mask_sum, dim3(1), dim3(128), 0, stream, mask, msum);
    hipLaunchKernelGGL(k_mean_ctx, dim3(BB*H/256), dim3(256), 0, stream, ctx, msum, meanc);
    hipLaunchKernelGGL((k_gemm_nt<1>), dim3(H/64, BB/64), dim3(256), 0, stream,
                       meanc, W_init, b_init, h0f, BB, H, H);
    hipLaunchKernelGGL(k_split_hl, dim3(BB*H/4/256), dim3(256), 0, stream, h0f, h0hi, h0lo, BB*H/4);

    hipLaunchKernelGGL(k_f2bf_frag, dim3(H3*DIN/8/256), dim3(256), 0, stream, W_ih0, Wih0f, H3*DIN/8, DIN/8);
    hipLaunchKernelGGL(k_f2bf_frag, dim3(H3*H/8/256), dim3(256), 0, stream, W_hh0, Whh0f, H3*H/8, H/8);
    hipLaunchKernelGGL(k_f2bf_frag, dim3(H3*H/8/256), dim3(256), 0, stream, W_ih1, Wih1f, H3*H/8, H/8);
    hipLaunchKernelGGL(k_f2bf_frag, dim3(H3*H/8/256), dim3(256), 0, stream, W_hh1, Whh1f, H3*H/8, H/8);
    hipLaunchKernelGGL(k_f2bf_frag, dim3(DIN*H/8/256), dim3(256), 0, stream, W_h2o, Wh2of, DIN*H/8, H/8);
    hipLaunchKernelGGL(k_f2bf_frag, dim3(H*H/8/256), dim3(256), 0, stream, W_c2c, Wc2cf, H*H/8, H/8);
    hipLaunchKernelGGL(k_transp_bf, dim3(32, 32), dim3(256), 0, stream, W_h2c, WTh2c);
    hipLaunchKernelGGL(k_rownorm_frag, dim3(VSZ/4), dim3(256), 0, stream, W_out, Woutf, VSZ);
    hipLaunchKernelGGL(k_f2bf_frag, dim3(SS*BB*H/8/256), dim3(256), 0, stream, ctx, ctxf, SS*BB*H/8, H/8);
    hipLaunchKernelGGL(k_emb_frag_hl, dim3(NROWS/4), dim3(256), 0, stream, emb_W, y, embfh, embfl);

    // ---- batched GEMMs ----
    hipLaunchKernelGGL((k_gemmf<1,1,0,u16>), dim3(H3/128, NROWS/128), dim3(256), 0, stream,
                       embfh, embfl, Wih0f, b_ih0, gi0b, NROWS, H3, DIN);
    hipLaunchKernelGGL((k_gemmf<1,0,0,u16>), dim3(H/128, SS*BB/128), dim3(256), 0, stream,
                       ctxf, (const u16*)nullptr, Wc2cf, (const float*)nullptr, ctxpb, SS*BB, H, H);

    // ---- recurrence: 3 kernels per step ----
    for (int t = 0; t < TP; t++){
        const u16*   hphi = t ? (h2allb + (size_t)(t-1)*BB*H) : h0hi;
        const u16*   hplo = t ? (((t-1) & 1) ? hloB : hloA) : h0lo;
        const float* hpf  = t ? (((t-1) & 1) ? hB : hA) : h0f;
        float*       h2f  = (t & 1) ? hB : hA;
        u16*         h2lo = (t & 1) ? hloB : hloA;
        hipLaunchKernelGGL(kA_gru0, dim3(128), dim3(256), 0, stream,
                           hphi, hplo, hpf, Whh0f, gi0b + (size_t)t*BB*H3, b_hh0, h1f, h1hi, h1lo);
        hipLaunchKernelGGL(kB_attn, dim3(BB), dim3(256), 0, stream,
                           h1f, WTh2c, ctxpb, v_att, mask, ctx, zthi, ztlo);
        hipLaunchKernelGGL(kC_gru1, dim3(128), dim3(256), 0, stream,
                           zthi, ztlo, h1hi, h1lo, h1f, Wih1f, Whh1f, b_ih1, b_hh1,
                           h2f, h2allb + (size_t)t*BB*H, h2lo);
    }

    // ---- output head ----
    hipLaunchKernelGGL((k_gemmf<0,0,1,float>), dim3(DIN/128, NROWS/128), dim3(256), 0, stream,
                       h2allb, (const u16*)nullptr, Wh2of, b_h2o, logitf, NROWS, DIN, H);
    hipLaunchKernelGGL(k_rownorm_frag, dim3(NROWS/4), dim3(256), 0, stream, logitf, logitfr, NROWS);
    hipLaunchKernelGGL(k_final, dim3(NROWS/128, VSZ/128), dim3(256), 0, stream,
                       logitfr, Woutf, y, pmax, strue);
    hipLaunchKernelGGL(k_loss, dim3((NROWS + 255)/256), dim3(256), 0, stream, pmax, strue, y, out);
}